// Round 3
// baseline (1213.958 us; speedup 1.0000x reference)
//
#include <hip/hip_runtime.h>
#include <hip/hip_bf16.h>

// GaussianGraphNetwork: 3-layer TransformerConv (PyG-style) on MI355X.
// All float I/O is FLOAT32 (NaN evidence from r2: f32 read as bf16 -> NaN).
// N=50000 nodes, E=800000 edges, all layers: din=64, H*C=64, skip=64, DE=32.
//
// Math refactor:
//   q·(k+e@We) = q·k + (We^T q)·ea      -> per-node qe[N,64], edge pass = 2 dots
//   sum_e a(v+ea@We) = sum a v + (sum a ea)@We  -> We applied once per node

#define NDIM 64

// ---------- CSR build ----------
__global__ void k_count(const int* __restrict__ ei, int* __restrict__ cnt, int E) {
  int i = blockIdx.x * blockDim.x + threadIdx.x;
  if (i < E) atomicAdd(&cnt[ei[E + i]], 1);  // row 1 = dst
}

__global__ __launch_bounds__(1024) void k_scan(const int* __restrict__ cnt,
                                               int* __restrict__ rowptr, int n) {
  const int T = 1024;
  int t = threadIdx.x;
  int chunk = (n + T - 1) / T;
  int begin = t * chunk;
  int end = begin + chunk; if (end > n) end = n;
  int sum = 0;
  for (int i = begin; i < end; ++i) sum += cnt[i];
  __shared__ int ps[T];
  ps[t] = sum;
  __syncthreads();
  for (int off = 1; off < T; off <<= 1) {
    int v = (t >= off) ? ps[t - off] : 0;
    __syncthreads();
    ps[t] += v;
    __syncthreads();
  }
  int prefix = (t == 0) ? 0 : ps[t - 1];
  for (int i = begin; i < end; ++i) { rowptr[i] = prefix; prefix += cnt[i]; }
  if (t == 0) rowptr[n] = ps[T - 1];
}

__global__ void k_scatter(const int* __restrict__ ei, int* __restrict__ fill,
                          const int* __restrict__ rowptr, int* __restrict__ srcs,
                          int* __restrict__ eids, int E) {
  int i = blockIdx.x * blockDim.x + threadIdx.x;
  if (i < E) {
    int d = ei[E + i];
    int pos = rowptr[d] + atomicAdd(&fill[d], 1);
    srcs[pos] = ei[i];
    eids[pos] = i;
  }
}

// ---------- node GEMM: h[N,64] @ {Wq|Wk|Wv|Ws}[64,64] + bias -> qkvs[N,256] f32 ----------
__global__ __launch_bounds__(256) void k_node(
    const float* __restrict__ h,
    const float* __restrict__ Wq, const float* __restrict__ bq,
    const float* __restrict__ Wk, const float* __restrict__ bk,
    const float* __restrict__ Wv, const float* __restrict__ bv,
    const float* __restrict__ Ws, const float* __restrict__ bs,
    float* __restrict__ qkvs, int N)
{
  __shared__ float hL[64][64];
  int t = threadIdx.x;
  int nb = blockIdx.x * 64;
  int m = t >> 6, c = t & 63;
  const float* W = (m == 0) ? Wq : (m == 1) ? Wk : (m == 2) ? Wv : Ws;
  const float* B = (m == 0) ? bq : (m == 1) ? bk : (m == 2) ? bv : bs;
  float w[64];
#pragma unroll
  for (int d = 0; d < 64; ++d) w[d] = W[d * 64 + c];
  float bias = B[c];
  int nmax = N - nb; if (nmax > 64) nmax = 64;
#pragma unroll
  for (int j = 0; j < 16; ++j) {
    int flat = j * 256 + t;
    int ni = flat >> 6;
    if (ni < nmax) hL[ni][flat & 63] = h[(size_t)(nb + ni) * 64 + (flat & 63)];
  }
  __syncthreads();
  for (int i = 0; i < nmax; ++i) {
    float acc = bias;
    const float4* hr = (const float4*)&hL[i][0];
#pragma unroll
    for (int d4 = 0; d4 < 16; ++d4) {
      float4 hv = hr[d4];
      acc = fmaf(hv.x, w[4 * d4 + 0], acc);
      acc = fmaf(hv.y, w[4 * d4 + 1], acc);
      acc = fmaf(hv.z, w[4 * d4 + 2], acc);
      acc = fmaf(hv.w, w[4 * d4 + 3], acc);
    }
    qkvs[(size_t)(nb + i) * 256 + t] = acc;
  }
}

// ---------- qe[n, h*32+d] = sum_c We[d][h*C+c] * q[n][h*C+c] ----------
template <int H>
__global__ void k_qe(const float* __restrict__ qkvs,
                     const float* __restrict__ We,
                     float* __restrict__ qe, int N)
{
  int gid = blockIdx.x * blockDim.x + threadIdx.x;
  if (gid >= N * 64) return;
  int n = gid >> 6, slot = gid & 63;
  if (H == 1 && slot >= 32) { qe[gid] = 0.f; return; }
  const int C = (H == 2) ? 32 : 64;
  int hh = (H == 2) ? (slot >> 5) : 0;
  int d = (H == 2) ? (slot & 31) : slot;
  const float* qrow = qkvs + (size_t)n * 256 + hh * C;
  const float* wrow = We + d * 64 + hh * C;
  float acc = 0.f;
#pragma unroll 8
  for (int c = 0; c < C; ++c) acc = fmaf(qrow[c], wrow[c], acc);
  qe[gid] = acc;
}

// ---------- fused attention per dst node: one wave (64 lanes = 64 channels) ----------
template <int H, bool LAST>
__global__ __launch_bounds__(256) void k_attn(
    const float* __restrict__ qkvs,   // [N][256]: q|k|v|skip
    const float* __restrict__ qe,     // [N][64]
    const float* __restrict__ ea,     // [E][32]
    const float* __restrict__ We,     // [32][64]
    const int* __restrict__ rowptr,
    const int* __restrict__ srcs,
    const int* __restrict__ eids,
    const float* __restrict__ prelu_a,
    float* __restrict__ hout,
    int N)
{
  int wave = threadIdx.x >> 6;
  int lane = threadIdx.x & 63;
  int dst = blockIdx.x * 4 + wave;
  if (dst >= N) return;
  const float rsC = (H == 2) ? 0.17677669529663687f : 0.125f;  // 1/sqrt(C)

  float q_c = qkvs[(size_t)dst * 256 + lane];
  float qe_c = qe[(size_t)dst * 64 + lane];
  float wecol[32];
#pragma unroll
  for (int d = 0; d < 32; ++d) wecol[d] = We[d * 64 + lane];

  float m = -1e30f, s = 0.f, accv = 0.f, acce = 0.f;
  int jb = rowptr[dst], je = rowptr[dst + 1];
  for (int j = jb; j < je; ++j) {
    int src = srcs[j];
    int eid = eids[j];
    float k_c = qkvs[(size_t)src * 256 + 64 + lane];
    float v_c = qkvs[(size_t)src * 256 + 128 + lane];
    float ea_c = ea[(size_t)eid * 32 + (lane & 31)];
    float r = q_c * k_c + qe_c * ea_c;
#pragma unroll
    for (int off = 1; off < ((H == 2) ? 32 : 64); off <<= 1) r += __shfl_xor(r, off);
    float alpha = r * rsC;
    float mn = fmaxf(m, alpha);
    float sc = __expf(m - mn);      // 0 on first edge, 1 if max unchanged
    float p = __expf(alpha - mn);
    s = s * sc + p;
    accv = accv * sc + p * v_c;
    acce = acce * sc + p * ea_c;
    m = mn;
  }

  // epilogue: out = (accv + aea @ We) / (s+eps) + skip [; prelu]
  int base = (H == 2) ? (lane & 32) : 0;
  float sum = accv;
#pragma unroll
  for (int d = 0; d < 32; ++d) {
    float aead = __shfl(acce, base + d);
    sum = fmaf(aead, wecol[d], sum);
  }
  float out = sum / (s + 1e-16f);
  out += qkvs[(size_t)dst * 256 + 192 + lane];
  if (!LAST) {
    float a = prelu_a[0];
    out = (out >= 0.f) ? out : a * out;
  }
  hout[(size_t)dst * 64 + lane] = out;
}

extern "C" void kernel_launch(void* const* d_in, const int* in_sizes, int n_in,
                              void* d_out, int out_size, void* d_ws, size_t ws_size,
                              hipStream_t stream) {
  const int N = in_sizes[0] / NDIM;   // 50000
  const int E = in_sizes[2] / 2;      // 800000

  const float* x  = (const float*)d_in[0];
  const float* ea = (const float*)d_in[1];
  const int* ei   = (const int*)d_in[2];
  const float* prelu = (const float*)d_in[30];
  auto W = [&](int l, int k) { return (const float*)d_in[3 + 9 * l + k]; };
  // k: 0=Wq 1=bq 2=Wk 3=bk 4=Wv 5=bv 6=We 7=Ws 8=bs

  char* p = (char*)d_ws;
  auto alloc = [&](size_t bytes) { char* r = p; p += (bytes + 255) & ~(size_t)255; return r; };
  float* h       = (float*)alloc((size_t)N * 64 * 4);
  float* qkvs    = (float*)alloc((size_t)N * 256 * 4);
  float* qe      = (float*)alloc((size_t)N * 64 * 4);
  int* rowptr    = (int*)alloc((size_t)(N + 1) * 4);
  int* cnt       = (int*)alloc((size_t)N * 4);
  int* fill      = (int*)alloc((size_t)N * 4);
  int* srcs      = (int*)alloc((size_t)E * 4);
  int* eids      = (int*)alloc((size_t)E * 4);
  (void)ws_size; (void)n_in; (void)out_size;

  hipMemsetAsync(cnt, 0, (size_t)N * 4, stream);
  hipMemsetAsync(fill, 0, (size_t)N * 4, stream);

  k_count<<<(E + 255) / 256, 256, 0, stream>>>(ei, cnt, E);
  k_scan<<<1, 1024, 0, stream>>>(cnt, rowptr, N);
  k_scatter<<<(E + 255) / 256, 256, 0, stream>>>(ei, fill, rowptr, srcs, eids, E);

  for (int l = 0; l < 3; ++l) {
    const float* hin = (l == 0) ? x : h;
    k_node<<<(N + 63) / 64, 256, 0, stream>>>(
        hin, W(l, 0), W(l, 1), W(l, 2), W(l, 3), W(l, 4), W(l, 5), W(l, 7), W(l, 8), qkvs, N);
    if (l < 2) {
      k_qe<2><<<(N * 64 + 255) / 256, 256, 0, stream>>>(qkvs, W(l, 6), qe, N);
      k_attn<2, false><<<(N + 3) / 4, 256, 0, stream>>>(
          qkvs, qe, ea, W(l, 6), rowptr, srcs, eids, prelu, h, N);
    } else {
      k_qe<1><<<(N * 64 + 255) / 256, 256, 0, stream>>>(qkvs, W(l, 6), qe, N);
      k_attn<1, true><<<(N + 3) / 4, 256, 0, stream>>>(
          qkvs, qe, ea, W(l, 6), rowptr, srcs, eids, prelu, (float*)d_out, N);
    }
  }
}

// Round 4
// 899.226 us; speedup vs baseline: 1.3500x; 1.3500x over previous
//
#include <hip/hip_runtime.h>
#include <hip/hip_bf16.h>

// GaussianGraphNetwork: 3-layer TransformerConv (PyG-style) on MI355X. f32 I/O.
// N=50000, E=800000, all layers din=64, H*C=64, skip=64, DE=32.
// r3 profile: k_attn latency-bound (VALU 28%, HBM 17%). r4: unroll x4 + bf16 k/v/ea gather.

#define NDIM 64

static __device__ __forceinline__ float b2f(__hip_bfloat16 v) { return __bfloat162float(v); }
static __device__ __forceinline__ unsigned short f2bu(float f) {
  __hip_bfloat16 b = __float2bfloat16(f);
  return *reinterpret_cast<unsigned short*>(&b);
}

// ---------- edge_attr f32 -> bf16, once per launch ----------
__global__ void k_cvt_ea(const float4* __restrict__ ea, ushort4* __restrict__ eab, int n4) {
  int i = blockIdx.x * blockDim.x + threadIdx.x;
  if (i < n4) {
    float4 v = ea[i];
    ushort4 o;
    o.x = f2bu(v.x); o.y = f2bu(v.y); o.z = f2bu(v.z); o.w = f2bu(v.w);
    eab[i] = o;
  }
}

// ---------- CSR build ----------
__global__ void k_count(const int* __restrict__ ei, int* __restrict__ cnt, int E) {
  int i = blockIdx.x * blockDim.x + threadIdx.x;
  if (i < E) atomicAdd(&cnt[ei[E + i]], 1);  // row 1 = dst
}

__global__ __launch_bounds__(1024) void k_scan(const int* __restrict__ cnt,
                                               int* __restrict__ rowptr, int n) {
  const int T = 1024;
  int t = threadIdx.x;
  int chunk = (n + T - 1) / T;
  int begin = t * chunk;
  int end = begin + chunk; if (end > n) end = n;
  int sum = 0;
  for (int i = begin; i < end; ++i) sum += cnt[i];
  __shared__ int ps[T];
  ps[t] = sum;
  __syncthreads();
  for (int off = 1; off < T; off <<= 1) {
    int v = (t >= off) ? ps[t - off] : 0;
    __syncthreads();
    ps[t] += v;
    __syncthreads();
  }
  int prefix = (t == 0) ? 0 : ps[t - 1];
  for (int i = begin; i < end; ++i) { rowptr[i] = prefix; prefix += cnt[i]; }
  if (t == 0) rowptr[n] = ps[T - 1];
}

__global__ void k_scatter(const int* __restrict__ ei, int* __restrict__ fill,
                          const int* __restrict__ rowptr, int2* __restrict__ pairs, int E) {
  int i = blockIdx.x * blockDim.x + threadIdx.x;
  if (i < E) {
    int d = ei[E + i];
    int pos = rowptr[d] + atomicAdd(&fill[d], 1);
    pairs[pos] = make_int2(ei[i], i);  // (src, eid)
  }
}

// ---------- node GEMM: h[N,64] @ {Wq|Wk|Wv|Ws}[64,64] + bias ----------
// outputs: qs f32 [N][128] = q|skip ; kvb bf16 [N][128] = k|v
__global__ __launch_bounds__(256) void k_node(
    const float* __restrict__ h,
    const float* __restrict__ Wq, const float* __restrict__ bq,
    const float* __restrict__ Wk, const float* __restrict__ bk,
    const float* __restrict__ Wv, const float* __restrict__ bv,
    const float* __restrict__ Ws, const float* __restrict__ bs,
    float* __restrict__ qs, __hip_bfloat16* __restrict__ kvb, int N)
{
  __shared__ float hL[64][64];
  int t = threadIdx.x;
  int nb = blockIdx.x * 64;
  int m = t >> 6, c = t & 63;
  const float* W = (m == 0) ? Wq : (m == 1) ? Wk : (m == 2) ? Wv : Ws;
  const float* B = (m == 0) ? bq : (m == 1) ? bk : (m == 2) ? bv : bs;
  float w[64];
#pragma unroll
  for (int d = 0; d < 64; ++d) w[d] = W[d * 64 + c];
  float bias = B[c];
  int nmax = N - nb; if (nmax > 64) nmax = 64;
#pragma unroll
  for (int j = 0; j < 16; ++j) {
    int flat = j * 256 + t;
    int ni = flat >> 6;
    if (ni < nmax) hL[ni][flat & 63] = h[(size_t)(nb + ni) * 64 + (flat & 63)];
  }
  __syncthreads();
  for (int i = 0; i < nmax; ++i) {
    float acc = bias;
    const float4* hr = (const float4*)&hL[i][0];
#pragma unroll
    for (int d4 = 0; d4 < 16; ++d4) {
      float4 hv = hr[d4];
      acc = fmaf(hv.x, w[4 * d4 + 0], acc);
      acc = fmaf(hv.y, w[4 * d4 + 1], acc);
      acc = fmaf(hv.z, w[4 * d4 + 2], acc);
      acc = fmaf(hv.w, w[4 * d4 + 3], acc);
    }
    size_t n = (size_t)(nb + i);
    if (m == 0)      qs[n * 128 + c] = acc;
    else if (m == 3) qs[n * 128 + 64 + c] = acc;
    else             kvb[n * 128 + ((m == 2) ? 64 : 0) + c] = __float2bfloat16(acc);
  }
}

// ---------- qe[n, slot] : We^T q per node ----------
template <int H>
__global__ __launch_bounds__(256) void k_qe(const float* __restrict__ qs,
                                            const float* __restrict__ We,
                                            float* __restrict__ qe, int N)
{
  __shared__ float WeT[64][32];  // WeT[hc][d] = We[d][hc]
  int t = threadIdx.x;
#pragma unroll
  for (int f = t; f < 2048; f += 256) WeT[f >> 5][f & 31] = We[(f & 31) * 64 + (f >> 5)];
  __syncthreads();
  int gid = blockIdx.x * 256 + t;
  if (gid >= N * 64) return;
  int n = gid >> 6, slot = gid & 63;
  if (H == 1 && slot >= 32) { qe[gid] = 0.f; return; }
  float acc = 0.f;
  if (H == 2) {
    int hh = slot >> 5, d = slot & 31;
    const float* qrow = qs + (size_t)n * 128 + hh * 32;
#pragma unroll
    for (int c = 0; c < 32; ++c) acc = fmaf(qrow[c], WeT[hh * 32 + c][d], acc);
  } else {
    int d = slot;
    const float* qrow = qs + (size_t)n * 128;
#pragma unroll
    for (int c = 0; c < 64; ++c) acc = fmaf(qrow[c], WeT[c][d], acc);
  }
  qe[gid] = acc;
}

// ---------- fused attention per dst node: one wave = one dst, lane = channel ----------
template <int H, bool LAST>
__global__ __launch_bounds__(256) void k_attn(
    const float* __restrict__ qs,            // [N][128]: q|skip
    const __hip_bfloat16* __restrict__ kvb,  // [N][128]: k|v
    const float* __restrict__ qe,            // [N][64]
    const __hip_bfloat16* __restrict__ eab,  // [E][32]
    const float* __restrict__ We,            // [32][64]
    const int* __restrict__ rowptr,
    const int2* __restrict__ pairs,          // (src, eid)
    const float* __restrict__ prelu_a,
    float* __restrict__ hout, int N)
{
  int wave = threadIdx.x >> 6;
  int lane = threadIdx.x & 63;
  int dst = blockIdx.x * 4 + wave;
  if (dst >= N) return;
  const float rsC = (H == 2) ? 0.17677669529663687f : 0.125f;
  const int RW = (H == 2) ? 32 : 64;

  float q_c = qs[(size_t)dst * 128 + lane];
  float qe_c = qe[(size_t)dst * 64 + lane];

  float m = -1e30f, s = 0.f, accv = 0.f, acce = 0.f;
  int jb = rowptr[dst], je = rowptr[dst + 1];
  int j = jb;
  for (; j + 4 <= je; j += 4) {
    int2 p0 = pairs[j], p1 = pairs[j + 1], p2 = pairs[j + 2], p3 = pairs[j + 3];
    const __hip_bfloat16* r0 = kvb + (size_t)p0.x * 128;
    const __hip_bfloat16* r1 = kvb + (size_t)p1.x * 128;
    const __hip_bfloat16* r2 = kvb + (size_t)p2.x * 128;
    const __hip_bfloat16* r3 = kvb + (size_t)p3.x * 128;
    float k0 = b2f(r0[lane]), v0 = b2f(r0[64 + lane]);
    float k1 = b2f(r1[lane]), v1 = b2f(r1[64 + lane]);
    float k2 = b2f(r2[lane]), v2 = b2f(r2[64 + lane]);
    float k3 = b2f(r3[lane]), v3 = b2f(r3[64 + lane]);
    int el = lane & 31;
    float a0 = b2f(eab[(size_t)p0.y * 32 + el]);
    float a1 = b2f(eab[(size_t)p1.y * 32 + el]);
    float a2 = b2f(eab[(size_t)p2.y * 32 + el]);
    float a3 = b2f(eab[(size_t)p3.y * 32 + el]);
    float x0 = fmaf(q_c, k0, qe_c * a0);
    float x1 = fmaf(q_c, k1, qe_c * a1);
    float x2 = fmaf(q_c, k2, qe_c * a2);
    float x3 = fmaf(q_c, k3, qe_c * a3);
#pragma unroll
    for (int off = 1; off < RW; off <<= 1) {
      x0 += __shfl_xor(x0, off);
      x1 += __shfl_xor(x1, off);
      x2 += __shfl_xor(x2, off);
      x3 += __shfl_xor(x3, off);
    }
    x0 *= rsC; x1 *= rsC; x2 *= rsC; x3 *= rsC;
    float mx = fmaxf(fmaxf(x0, x1), fmaxf(x2, x3));
    float mn = fmaxf(m, mx);
    float sc = __expf(m - mn);
    float q0 = __expf(x0 - mn), q1 = __expf(x1 - mn);
    float q2 = __expf(x2 - mn), q3 = __expf(x3 - mn);
    s = s * sc + ((q0 + q1) + (q2 + q3));
    accv = accv * sc + (fmaf(q0, v0, q1 * v1) + fmaf(q2, v2, q3 * v3));
    acce = acce * sc + (fmaf(q0, a0, q1 * a1) + fmaf(q2, a2, q3 * a3));
    m = mn;
  }
  for (; j < je; ++j) {
    int2 p0 = pairs[j];
    const __hip_bfloat16* r0 = kvb + (size_t)p0.x * 128;
    float k0 = b2f(r0[lane]), v0 = b2f(r0[64 + lane]);
    float a0 = b2f(eab[(size_t)p0.y * 32 + (lane & 31)]);
    float x0 = fmaf(q_c, k0, qe_c * a0);
#pragma unroll
    for (int off = 1; off < RW; off <<= 1) x0 += __shfl_xor(x0, off);
    x0 *= rsC;
    float mn = fmaxf(m, x0);
    float sc = __expf(m - mn);
    float q0 = __expf(x0 - mn);
    s = s * sc + q0;
    accv = accv * sc + q0 * v0;
    acce = acce * sc + q0 * a0;
    m = mn;
  }

  // epilogue: out = (accv + aea @ We)/(s+eps) + skip [; prelu]
  float wecol[32];
#pragma unroll
  for (int d = 0; d < 32; ++d) wecol[d] = We[d * 64 + lane];
  int base = (H == 2) ? (lane & 32) : 0;
  float sum = accv;
#pragma unroll
  for (int d = 0; d < 32; ++d) {
    float aead = __shfl(acce, base + d);
    sum = fmaf(aead, wecol[d], sum);
  }
  float out = sum / (s + 1e-16f);
  out += qs[(size_t)dst * 128 + 64 + lane];
  if (!LAST) {
    float a = prelu_a[0];
    out = (out >= 0.f) ? out : a * out;
  }
  hout[(size_t)dst * 64 + lane] = out;
}

extern "C" void kernel_launch(void* const* d_in, const int* in_sizes, int n_in,
                              void* d_out, int out_size, void* d_ws, size_t ws_size,
                              hipStream_t stream) {
  const int N = in_sizes[0] / NDIM;   // 50000
  const int E = in_sizes[2] / 2;      // 800000

  const float* x  = (const float*)d_in[0];
  const float* ea = (const float*)d_in[1];
  const int* ei   = (const int*)d_in[2];
  const float* prelu = (const float*)d_in[30];
  auto W = [&](int l, int k) { return (const float*)d_in[3 + 9 * l + k]; };
  // k: 0=Wq 1=bq 2=Wk 3=bk 4=Wv 5=bv 6=We 7=Ws 8=bs

  char* p = (char*)d_ws;
  auto alloc = [&](size_t bytes) { char* r = p; p += (bytes + 255) & ~(size_t)255; return r; };
  float* h             = (float*)alloc((size_t)N * 64 * 4);
  float* qs            = (float*)alloc((size_t)N * 128 * 4);
  __hip_bfloat16* kvb  = (__hip_bfloat16*)alloc((size_t)N * 128 * 2);
  float* qe            = (float*)alloc((size_t)N * 64 * 4);
  __hip_bfloat16* eab  = (__hip_bfloat16*)alloc((size_t)E * 32 * 2);
  int* rowptr          = (int*)alloc((size_t)(N + 1) * 4);
  int* cnt             = (int*)alloc((size_t)N * 4);
  int* fill            = (int*)alloc((size_t)N * 4);
  int2* pairs          = (int2*)alloc((size_t)E * 8);
  (void)ws_size; (void)n_in; (void)out_size;

  hipMemsetAsync(cnt, 0, (size_t)N * 4, stream);
  hipMemsetAsync(fill, 0, (size_t)N * 4, stream);

  k_cvt_ea<<<(E * 8 + 255) / 256, 256, 0, stream>>>((const float4*)ea, (ushort4*)eab, E * 8);
  k_count<<<(E + 255) / 256, 256, 0, stream>>>(ei, cnt, E);
  k_scan<<<1, 1024, 0, stream>>>(cnt, rowptr, N);
  k_scatter<<<(E + 255) / 256, 256, 0, stream>>>(ei, fill, rowptr, pairs, E);

  for (int l = 0; l < 3; ++l) {
    const float* hin = (l == 0) ? x : h;
    k_node<<<(N + 63) / 64, 256, 0, stream>>>(
        hin, W(l, 0), W(l, 1), W(l, 2), W(l, 3), W(l, 4), W(l, 5), W(l, 7), W(l, 8), qs, kvb, N);
    if (l < 2) {
      k_qe<2><<<(N * 64 + 255) / 256, 256, 0, stream>>>(qs, W(l, 6), qe, N);
      k_attn<2, false><<<(N + 3) / 4, 256, 0, stream>>>(
          qs, kvb, qe, eab, W(l, 6), rowptr, pairs, prelu, h, N);
    } else {
      k_qe<1><<<(N * 64 + 255) / 256, 256, 0, stream>>>(qs, W(l, 6), qe, N);
      k_attn<1, true><<<(N + 3) / 4, 256, 0, stream>>>(
          qs, kvb, qe, eab, W(l, 6), rowptr, pairs, prelu, (float*)d_out, N);
    }
  }
}

// Round 6
// 814.400 us; speedup vs baseline: 1.4906x; 1.1042x over previous
//
#include <hip/hip_runtime.h>
#include <hip/hip_bf16.h>

// GaussianGraphNetwork: 3-layer TransformerConv (PyG-style) on MI355X. f32 I/O.
// N=50000, E=800000, all layers din=64, H*C=64, skip=64, DE=32.
// r4: k_attn 87us (VALU 60%, FETCH 160MB) -> r5: CSR-ordered edge_attr (streamed),
// fused convert+permute into scatter, parallel 3-phase scan.

#define NDIM 64

static __device__ __forceinline__ float b2f(__hip_bfloat16 v) { return __bfloat162float(v); }
static __device__ __forceinline__ unsigned short f2bu(float f) {
  __hip_bfloat16 b = __float2bfloat16(f);
  return *reinterpret_cast<unsigned short*>(&b);
}

// ---------- CSR build ----------
__global__ void k_count(const int* __restrict__ ei, int* __restrict__ cnt, int E) {
  int i = blockIdx.x * blockDim.x + threadIdx.x;
  if (i < E) atomicAdd(&cnt[ei[E + i]], 1);  // row 1 = dst
}

// scan phase A: per-block (1024 el) local scan; 4 el/thread
__global__ __launch_bounds__(256) void k_scanA(const int* __restrict__ cnt,
                                               int* __restrict__ tpre,
                                               int* __restrict__ btot, int n) {
  int t = threadIdx.x, b = blockIdx.x;
  int base = (b * 256 + t) * 4;
  int s = 0;
  if (base + 3 < n) {
    int4 v = *(const int4*)(cnt + base);
    s = v.x + v.y + v.z + v.w;
  } else if (base < n) {
    for (int k = 0; k < 4 && base + k < n; ++k) s += cnt[base + k];
  }
  __shared__ int ps[256];
  ps[t] = s;
  __syncthreads();
  for (int off = 1; off < 256; off <<= 1) {
    int v = (t >= off) ? ps[t - off] : 0;
    __syncthreads();
    ps[t] += v;
    __syncthreads();
  }
  tpre[b * 256 + t] = ps[t] - s;  // exclusive prefix of this thread's 4-group
  if (t == 255) btot[b] = ps[255];
}

// scan phase B: one wave scans block totals (nb <= 64), writes rowptr[n] = E
__global__ void k_scanB(int* __restrict__ btot, int nb, int* __restrict__ rowptr, int n) {
  int lane = threadIdx.x & 63;
  int v = (lane < nb) ? btot[lane] : 0;
  int inc = v;
#pragma unroll
  for (int off = 1; off < 64; off <<= 1) {
    int u = __shfl_up(inc, off);
    if (lane >= off) inc += u;
  }
  if (lane < nb) btot[lane] = inc - v;  // exclusive block offset
  if (lane == 63) rowptr[n] = inc;      // grand total = E
}

// scan phase C: rowptr[e] = btot[b] + tpre + running
__global__ __launch_bounds__(256) void k_scanC(const int* __restrict__ cnt,
                                               const int* __restrict__ tpre,
                                               const int* __restrict__ btot,
                                               int* __restrict__ rowptr, int n) {
  int t = threadIdx.x, b = blockIdx.x;
  int base = (b * 256 + t) * 4;
  if (base >= n) return;
  int p = btot[b] + tpre[b * 256 + t];
  if (base + 3 < n) {
    int4 v = *(const int4*)(cnt + base);
    rowptr[base] = p; p += v.x;
    rowptr[base + 1] = p; p += v.y;
    rowptr[base + 2] = p; p += v.z;
    rowptr[base + 3] = p;
  } else {
    for (int k = 0; k < 4 && base + k < n; ++k) { rowptr[base + k] = p; p += cnt[base + k]; }
  }
}

// scatter + edge_attr permute/convert: eab[pos] = bf16(ea[i]), srcs[pos] = src
__global__ void k_scatter(const int* __restrict__ ei, int* __restrict__ fill,
                          const int* __restrict__ rowptr,
                          const float4* __restrict__ ea,
                          int* __restrict__ srcs, ushort4* __restrict__ eab, int E) {
  int i = blockIdx.x * blockDim.x + threadIdx.x;
  if (i < E) {
    int d = ei[E + i];
    int pos = rowptr[d] + atomicAdd(&fill[d], 1);
    srcs[pos] = ei[i];
    const float4* s = ea + (size_t)i * 8;
    ushort4* o = eab + (size_t)pos * 8;
#pragma unroll
    for (int j = 0; j < 8; ++j) {
      float4 v = s[j];
      ushort4 u;
      u.x = f2bu(v.x); u.y = f2bu(v.y); u.z = f2bu(v.z); u.w = f2bu(v.w);
      o[j] = u;
    }
  }
}

// ---------- node GEMM: h[N,64] @ {Wq|Wk|Wv|Ws}[64,64] + bias ----------
// outputs: qs f32 [N][128] = q|skip ; kvb bf16 [N][128] = k|v
__global__ __launch_bounds__(256) void k_node(
    const float* __restrict__ h,
    const float* __restrict__ Wq, const float* __restrict__ bq,
    const float* __restrict__ Wk, const float* __restrict__ bk,
    const float* __restrict__ Wv, const float* __restrict__ bv,
    const float* __restrict__ Ws, const float* __restrict__ bs,
    float* __restrict__ qs, __hip_bfloat16* __restrict__ kvb, int N)
{
  __shared__ float hL[64][64];
  int t = threadIdx.x;
  int nb = blockIdx.x * 64;
  int m = t >> 6, c = t & 63;
  const float* W = (m == 0) ? Wq : (m == 1) ? Wk : (m == 2) ? Wv : Ws;
  const float* B = (m == 0) ? bq : (m == 1) ? bk : (m == 2) ? bv : bs;
  float w[64];
#pragma unroll
  for (int d = 0; d < 64; ++d) w[d] = W[d * 64 + c];
  float bias = B[c];
  int nmax = N - nb; if (nmax > 64) nmax = 64;
#pragma unroll
  for (int j = 0; j < 16; ++j) {
    int flat = j * 256 + t;
    int ni = flat >> 6;
    if (ni < nmax) hL[ni][flat & 63] = h[(size_t)(nb + ni) * 64 + (flat & 63)];
  }
  __syncthreads();
  for (int i = 0; i < nmax; ++i) {
    float acc = bias;
    const float4* hr = (const float4*)&hL[i][0];
#pragma unroll
    for (int d4 = 0; d4 < 16; ++d4) {
      float4 hv = hr[d4];
      acc = fmaf(hv.x, w[4 * d4 + 0], acc);
      acc = fmaf(hv.y, w[4 * d4 + 1], acc);
      acc = fmaf(hv.z, w[4 * d4 + 2], acc);
      acc = fmaf(hv.w, w[4 * d4 + 3], acc);
    }
    size_t n = (size_t)(nb + i);
    if (m == 0)      qs[n * 128 + c] = acc;
    else if (m == 3) qs[n * 128 + 64 + c] = acc;
    else             kvb[n * 128 + ((m == 2) ? 64 : 0) + c] = __float2bfloat16(acc);
  }
}

// ---------- qe[n, slot] : We^T q per node ----------
template <int H>
__global__ __launch_bounds__(256) void k_qe(const float* __restrict__ qs,
                                            const float* __restrict__ We,
                                            float* __restrict__ qe, int N)
{
  __shared__ float WeT[64][32];  // WeT[hc][d] = We[d][hc]
  int t = threadIdx.x;
#pragma unroll
  for (int f = t; f < 2048; f += 256) WeT[f >> 5][f & 31] = We[(f & 31) * 64 + (f >> 5)];
  __syncthreads();
  int gid = blockIdx.x * 256 + t;
  if (gid >= N * 64) return;
  int n = gid >> 6, slot = gid & 63;
  if (H == 1 && slot >= 32) { qe[gid] = 0.f; return; }
  float acc = 0.f;
  if (H == 2) {
    int hh = slot >> 5, d = slot & 31;
    const float* qrow = qs + (size_t)n * 128 + hh * 32;
#pragma unroll
    for (int c = 0; c < 32; ++c) acc = fmaf(qrow[c], WeT[hh * 32 + c][d], acc);
  } else {
    int d = slot;
    const float* qrow = qs + (size_t)n * 128;
#pragma unroll
    for (int c = 0; c < 64; ++c) acc = fmaf(qrow[c], WeT[c][d], acc);
  }
  qe[gid] = acc;
}

// ---------- fused attention per dst node: one wave = one dst, lane = channel ----------
template <int H, bool LAST>
__global__ __launch_bounds__(256) void k_attn(
    const float* __restrict__ qs,            // [N][128]: q|skip
    const __hip_bfloat16* __restrict__ kvb,  // [N][128]: k|v
    const float* __restrict__ qe,            // [N][64]
    const __hip_bfloat16* __restrict__ eab,  // [E][32] CSR-ordered
    const float* __restrict__ We,            // [32][64]
    const int* __restrict__ rowptr,
    const int* __restrict__ srcs,            // CSR-ordered src node ids
    const float* __restrict__ prelu_a,
    float* __restrict__ hout, int N)
{
  int wave = threadIdx.x >> 6;
  int lane = threadIdx.x & 63;
  int dst = blockIdx.x * 4 + wave;
  if (dst >= N) return;
  const float rsC = (H == 2) ? 0.17677669529663687f : 0.125f;
  const int RW = (H == 2) ? 32 : 64;
  int el = lane & 31;

  float q_c = qs[(size_t)dst * 128 + lane];
  float qe_c = qe[(size_t)dst * 64 + lane];

  float m = -1e30f, s = 0.f, accv = 0.f, acce = 0.f;
  int jb = rowptr[dst], je = rowptr[dst + 1];
  int j = jb;
  for (; j + 4 <= je; j += 4) {
    int s0 = srcs[j], s1 = srcs[j + 1], s2 = srcs[j + 2], s3 = srcs[j + 3];
    const __hip_bfloat16* r0 = kvb + (size_t)s0 * 128;
    const __hip_bfloat16* r1 = kvb + (size_t)s1 * 128;
    const __hip_bfloat16* r2 = kvb + (size_t)s2 * 128;
    const __hip_bfloat16* r3 = kvb + (size_t)s3 * 128;
    float k0 = b2f(r0[lane]), v0 = b2f(r0[64 + lane]);
    float k1 = b2f(r1[lane]), v1 = b2f(r1[64 + lane]);
    float k2 = b2f(r2[lane]), v2 = b2f(r2[64 + lane]);
    float k3 = b2f(r3[lane]), v3 = b2f(r3[64 + lane]);
    float a0 = b2f(eab[(size_t)(j + 0) * 32 + el]);
    float a1 = b2f(eab[(size_t)(j + 1) * 32 + el]);
    float a2 = b2f(eab[(size_t)(j + 2) * 32 + el]);
    float a3 = b2f(eab[(size_t)(j + 3) * 32 + el]);
    float x0 = fmaf(q_c, k0, qe_c * a0);
    float x1 = fmaf(q_c, k1, qe_c * a1);
    float x2 = fmaf(q_c, k2, qe_c * a2);
    float x3 = fmaf(q_c, k3, qe_c * a3);
#pragma unroll
    for (int off = 1; off < RW; off <<= 1) {
      x0 += __shfl_xor(x0, off);
      x1 += __shfl_xor(x1, off);
      x2 += __shfl_xor(x2, off);
      x3 += __shfl_xor(x3, off);
    }
    x0 *= rsC; x1 *= rsC; x2 *= rsC; x3 *= rsC;
    float mx = fmaxf(fmaxf(x0, x1), fmaxf(x2, x3));
    float mn = fmaxf(m, mx);
    float sc = __expf(m - mn);
    float q0 = __expf(x0 - mn), q1 = __expf(x1 - mn);
    float q2 = __expf(x2 - mn), q3 = __expf(x3 - mn);
    s = s * sc + ((q0 + q1) + (q2 + q3));
    accv = accv * sc + (fmaf(q0, v0, q1 * v1) + fmaf(q2, v2, q3 * v3));
    acce = acce * sc + (fmaf(q0, a0, q1 * a1) + fmaf(q2, a2, q3 * a3));
    m = mn;
  }
  for (; j < je; ++j) {
    int s0 = srcs[j];
    const __hip_bfloat16* r0 = kvb + (size_t)s0 * 128;
    float k0 = b2f(r0[lane]), v0 = b2f(r0[64 + lane]);
    float a0 = b2f(eab[(size_t)j * 32 + el]);
    float x0 = fmaf(q_c, k0, qe_c * a0);
#pragma unroll
    for (int off = 1; off < RW; off <<= 1) x0 += __shfl_xor(x0, off);
    x0 *= rsC;
    float mn = fmaxf(m, x0);
    float sc = __expf(m - mn);
    float q0 = __expf(x0 - mn);
    s = s * sc + q0;
    accv = accv * sc + q0 * v0;
    acce = acce * sc + q0 * a0;
    m = mn;
  }

  // epilogue: out = (accv + aea @ We)/(s+eps) + skip [; prelu]
  float wecol[32];
#pragma unroll
  for (int d = 0; d < 32; ++d) wecol[d] = We[d * 64 + lane];
  int base = (H == 2) ? (lane & 32) : 0;
  float sum = accv;
#pragma unroll
  for (int d = 0; d < 32; ++d) {
    float aead = __shfl(acce, base + d);
    sum = fmaf(aead, wecol[d], sum);
  }
  float out = sum / (s + 1e-16f);
  out += qs[(size_t)dst * 128 + 64 + lane];
  if (!LAST) {
    float a = prelu_a[0];
    out = (out >= 0.f) ? out : a * out;
  }
  hout[(size_t)dst * 64 + lane] = out;
}

extern "C" void kernel_launch(void* const* d_in, const int* in_sizes, int n_in,
                              void* d_out, int out_size, void* d_ws, size_t ws_size,
                              hipStream_t stream) {
  const int N = in_sizes[0] / NDIM;   // 50000
  const int E = in_sizes[2] / 2;      // 800000

  const float* x  = (const float*)d_in[0];
  const float* ea = (const float*)d_in[1];
  const int* ei   = (const int*)d_in[2];
  const float* prelu = (const float*)d_in[30];
  auto W = [&](int l, int k) { return (const float*)d_in[3 + 9 * l + k]; };
  // k: 0=Wq 1=bq 2=Wk 3=bk 4=Wv 5=bv 6=We 7=Ws 8=bs

  const int nbScan = (N + 1023) / 1024;  // 49

  char* p = (char*)d_ws;
  auto alloc = [&](size_t bytes) { char* r = p; p += (bytes + 255) & ~(size_t)255; return r; };
  float* h             = (float*)alloc((size_t)N * 64 * 4);
  float* qs            = (float*)alloc((size_t)N * 128 * 4);
  __hip_bfloat16* kvb  = (__hip_bfloat16*)alloc((size_t)N * 128 * 2);
  float* qe            = (float*)alloc((size_t)N * 64 * 4);
  __hip_bfloat16* eab  = (__hip_bfloat16*)alloc((size_t)E * 32 * 2);
  int* rowptr          = (int*)alloc((size_t)(N + 1) * 4);
  int* cnt             = (int*)alloc((size_t)N * 4);
  int* fill            = (int*)alloc((size_t)N * 4);
  int* srcs            = (int*)alloc((size_t)E * 4);
  int* tpre            = (int*)alloc((size_t)nbScan * 256 * 4);
  int* btot            = (int*)alloc((size_t)64 * 4);
  (void)ws_size; (void)n_in; (void)out_size;

  hipMemsetAsync(cnt, 0, (size_t)N * 4, stream);
  hipMemsetAsync(fill, 0, (size_t)N * 4, stream);

  k_count<<<(E + 255) / 256, 256, 0, stream>>>(ei, cnt, E);
  k_scanA<<<nbScan, 256, 0, stream>>>(cnt, tpre, btot, N);
  k_scanB<<<1, 64, 0, stream>>>(btot, nbScan, rowptr, N);
  k_scanC<<<nbScan, 256, 0, stream>>>(cnt, tpre, btot, rowptr, N);
  k_scatter<<<(E + 255) / 256, 256, 0, stream>>>(ei, fill, rowptr, (const float4*)ea,
                                                 srcs, (ushort4*)eab, E);

  for (int l = 0; l < 3; ++l) {
    const float* hin = (l == 0) ? x : h;
    k_node<<<(N + 63) / 64, 256, 0, stream>>>(
        hin, W(l, 0), W(l, 1), W(l, 2), W(l, 3), W(l, 4), W(l, 5), W(l, 7), W(l, 8), qs, kvb, N);
    if (l < 2) {
      k_qe<2><<<(N * 64 + 255) / 256, 256, 0, stream>>>(qs, W(l, 6), qe, N);
      k_attn<2, false><<<(N + 3) / 4, 256, 0, stream>>>(
          qs, kvb, qe, eab, W(l, 6), rowptr, srcs, prelu, h, N);
    } else {
      k_qe<1><<<(N * 64 + 255) / 256, 256, 0, stream>>>(qs, W(l, 6), qe, N);
      k_attn<1, true><<<(N + 3) / 4, 256, 0, stream>>>(
          qs, kvb, qe, eab, W(l, 6), rowptr, srcs, prelu, (float*)d_out, N);
    }
  }
}

// Round 7
// 784.157 us; speedup vs baseline: 1.5481x; 1.0386x over previous
//
#include <hip/hip_runtime.h>
#include <hip/hip_bf16.h>

// GaussianGraphNetwork: 3-layer TransformerConv (PyG-style) on MI355X. f32 I/O.
// N=50000, E=800000, all layers din=64, H*C=64, skip=64, DE=32.
// r6: k_attn 85us not fetch-bound (VALU 60%); ~400us unaccounted outside top-5.
// r7: interleaved k|v dword, exp2-domain softmax + defer-max, 4 dsts/wave,
//     coalesced-write eab permute (no scattered 64B RMW), qe fused into k_node,
//     dispatches 16 -> 13.

#define NDIM 64
#define LOG2E 1.4426950408889634f

static __device__ __forceinline__ unsigned short f2bu(float f) {
  __hip_bfloat16 b = __float2bfloat16(f);
  return *reinterpret_cast<unsigned short*>(&b);
}

// ---------- CSR build ----------
__global__ void k_count(const int* __restrict__ ei, int* __restrict__ cnt, int E) {
  int i = blockIdx.x * blockDim.x + threadIdx.x;
  if (i < E) atomicAdd(&cnt[ei[E + i]], 1);  // row 1 = dst
}

__global__ __launch_bounds__(256) void k_scanA(const int* __restrict__ cnt,
                                               int* __restrict__ tpre,
                                               int* __restrict__ btot, int n) {
  int t = threadIdx.x, b = blockIdx.x;
  int base = (b * 256 + t) * 4;
  int s = 0;
  if (base + 3 < n) {
    int4 v = *(const int4*)(cnt + base);
    s = v.x + v.y + v.z + v.w;
  } else if (base < n) {
    for (int k = 0; k < 4 && base + k < n; ++k) s += cnt[base + k];
  }
  __shared__ int ps[256];
  ps[t] = s;
  __syncthreads();
  for (int off = 1; off < 256; off <<= 1) {
    int v = (t >= off) ? ps[t - off] : 0;
    __syncthreads();
    ps[t] += v;
    __syncthreads();
  }
  tpre[b * 256 + t] = ps[t] - s;
  if (t == 255) btot[b] = ps[255];
}

__global__ void k_scanB(int* __restrict__ btot, int nb, int* __restrict__ rowptr, int n) {
  int lane = threadIdx.x & 63;
  int v = (lane < nb) ? btot[lane] : 0;
  int inc = v;
#pragma unroll
  for (int off = 1; off < 64; off <<= 1) {
    int u = __shfl_up(inc, off);
    if (lane >= off) inc += u;
  }
  if (lane < nb) btot[lane] = inc - v;
  if (lane == 63) rowptr[n] = inc;
}

__global__ __launch_bounds__(256) void k_scanC(const int* __restrict__ cnt,
                                               const int* __restrict__ tpre,
                                               const int* __restrict__ btot,
                                               int* __restrict__ rowptr, int n) {
  int t = threadIdx.x, b = blockIdx.x;
  int base = (b * 256 + t) * 4;
  if (base >= n) return;
  int p = btot[b] + tpre[b * 256 + t];
  if (base + 3 < n) {
    int4 v = *(const int4*)(cnt + base);
    rowptr[base] = p; p += v.x;
    rowptr[base + 1] = p; p += v.y;
    rowptr[base + 2] = p; p += v.z;
    rowptr[base + 3] = p;
  } else {
    for (int k = 0; k < 4 && base + k < n; ++k) { rowptr[base + k] = p; p += cnt[base + k]; }
  }
}

// scatter: only index traffic (8B/edge scattered). Heavy eab permute done coalesced below.
__global__ void k_scatter(const int* __restrict__ ei, int* __restrict__ fill,
                          const int* __restrict__ rowptr,
                          int* __restrict__ srcs, int* __restrict__ perm, int E) {
  int i = blockIdx.x * blockDim.x + threadIdx.x;
  if (i < E) {
    int d = ei[E + i];
    int pos = rowptr[d] + atomicAdd(&fill[d], 1);
    srcs[pos] = ei[i];
    perm[pos] = i;
  }
}

// eab[pos] = bf16(ea[perm[pos]]): coalesced writes, 128B-burst random reads.
__global__ __launch_bounds__(256) void k_permea(const int* __restrict__ perm,
                                                const float4* __restrict__ ea,
                                                ushort4* __restrict__ eab, int E) {
  int tid = blockIdx.x * 256 + threadIdx.x;
  int pos = tid >> 3, t = tid & 7;
  if (pos >= E) return;
  int i = perm[pos];
  float4 v = ea[(size_t)i * 8 + t];
  ushort4 u;
  u.x = f2bu(v.x); u.y = f2bu(v.y); u.z = f2bu(v.z); u.w = f2bu(v.w);
  eab[(size_t)pos * 8 + t] = u;
}

// ---------- node GEMM + fused qe ----------
// outputs: qs f32 [N][128] = q|skip ; kvw uint [N][64] = (v<<16|k) per channel ;
//          qe f32 [N][64]
template <int H>
__global__ __launch_bounds__(256) void k_node(
    const float* __restrict__ h,
    const float* __restrict__ Wq, const float* __restrict__ bq,
    const float* __restrict__ Wk, const float* __restrict__ bk,
    const float* __restrict__ Wv, const float* __restrict__ bv,
    const float* __restrict__ Ws, const float* __restrict__ bs,
    const float* __restrict__ We,
    float* __restrict__ qs, unsigned int* __restrict__ kvw,
    float* __restrict__ qe, int N)
{
  __shared__ float hL[64][64];
  __shared__ float qL[64][64];
  __shared__ float WeT[2048];  // WeT[hc*32+d] = We[d*64+hc]
  int t = threadIdx.x;
  int nb = blockIdx.x * 64;
  int m = t >> 6, c = t & 63;
  const float* W = (m == 0) ? Wq : (m == 1) ? Wk : (m == 2) ? Wv : Ws;
  const float* B = (m == 0) ? bq : (m == 1) ? bk : (m == 2) ? bv : bs;
  float w[64];
#pragma unroll
  for (int d = 0; d < 64; ++d) w[d] = W[d * 64 + c];
  float bias = B[c];
#pragma unroll
  for (int f = t; f < 2048; f += 256) WeT[(f >> 5) * 32 + (f & 31)] = We[(f & 31) * 64 + (f >> 5)];
  int nmax = N - nb; if (nmax > 64) nmax = 64;
#pragma unroll
  for (int j = 0; j < 16; ++j) {
    int flat = j * 256 + t;
    int ni = flat >> 6;
    if (ni < nmax) hL[ni][flat & 63] = h[(size_t)(nb + ni) * 64 + (flat & 63)];
  }
  __syncthreads();
  for (int i = 0; i < nmax; ++i) {
    float acc = bias;
    const float4* hr = (const float4*)&hL[i][0];
#pragma unroll
    for (int d4 = 0; d4 < 16; ++d4) {
      float4 hv = hr[d4];
      acc = fmaf(hv.x, w[4 * d4 + 0], acc);
      acc = fmaf(hv.y, w[4 * d4 + 1], acc);
      acc = fmaf(hv.z, w[4 * d4 + 2], acc);
      acc = fmaf(hv.w, w[4 * d4 + 3], acc);
    }
    size_t n = (size_t)(nb + i);
    if (m == 0)      { qs[n * 128 + c] = acc; qL[i][c] = acc; }
    else if (m == 3) qs[n * 128 + 64 + c] = acc;
    else ((unsigned short*)kvw)[(n * 64 + c) * 2 + (m == 2 ? 1 : 0)] = f2bu(acc);
  }
  __syncthreads();
  // qe phase: slot = t&63, 16 nodes per thread group; half = slot>>5 covers c-range.
  int slot = t & 63, ibase = (t >> 6) * 16;
  int half = slot >> 5, d = slot & 31;
  float wreg[32];
#pragma unroll
  for (int cc = 0; cc < 32; ++cc) wreg[cc] = WeT[(half * 32 + cc) * 32 + d];
  for (int ii = 0; ii < 16; ++ii) {
    int i = ibase + ii;
    if (i >= nmax) break;
    float acc = 0.f;
    const float4* qr = (const float4*)&qL[i][half * 32];
#pragma unroll
    for (int c4 = 0; c4 < 8; ++c4) {
      float4 qv = qr[c4];
      acc = fmaf(qv.x, wreg[4 * c4 + 0], acc);
      acc = fmaf(qv.y, wreg[4 * c4 + 1], acc);
      acc = fmaf(qv.z, wreg[4 * c4 + 2], acc);
      acc = fmaf(qv.w, wreg[4 * c4 + 3], acc);
    }
    size_t n = (size_t)(nb + i);
    if (H == 2) {
      qe[n * 64 + slot] = acc;          // head = half, dim = d
    } else {
      float tot = acc + __shfl_xor(acc, 32);
      qe[n * 64 + slot] = (slot < 32) ? tot : 0.f;
    }
  }
}

// ---------- fused attention: one wave = 4 strided dsts, lane = channel ----------
template <int H, bool LAST>
__global__ __launch_bounds__(256) void k_attn(
    const float* __restrict__ qs,            // [N][128]: q|skip
    const unsigned int* __restrict__ kvw,    // [N][64]: v<<16|k
    const float* __restrict__ qe,            // [N][64]
    const __hip_bfloat16* __restrict__ eab,  // [E][32] CSR-ordered
    const float* __restrict__ We,            // [32][64]
    const int* __restrict__ rowptr,
    const int* __restrict__ srcs,
    const float* __restrict__ prelu_a,
    float* __restrict__ hout, int N)
{
  int wave = threadIdx.x >> 6;
  int lane = threadIdx.x & 63;
  int wgid = blockIdx.x * 4 + wave;
  const int W = gridDim.x * 4;
  const float pmul = ((H == 2) ? 0.17677669529663687f : 0.125f) * LOG2E;
  const int RW = (H == 2) ? 32 : 64;
  int el = lane & 31;

  float wecol[32];
#pragma unroll
  for (int d = 0; d < 32; ++d) wecol[d] = We[d * 64 + lane];
  float pa = LAST ? 0.f : prelu_a[0];

  for (int rep = 0; rep < 4; ++rep) {
    int dst = wgid + rep * W;
    if (dst >= N) break;

    float q_c = qs[(size_t)dst * 128 + lane] * pmul;
    float qe_c = qe[(size_t)dst * 64 + lane] * pmul;

    float m = -1e30f, s = 0.f, accv = 0.f, acce = 0.f;
    int jb = rowptr[dst], je = rowptr[dst + 1];
    int j = jb;
    for (; j + 4 <= je; j += 4) {
      int s0 = srcs[j], s1 = srcs[j + 1], s2 = srcs[j + 2], s3 = srcs[j + 3];
      unsigned int w0 = kvw[(size_t)s0 * 64 + lane];
      unsigned int w1 = kvw[(size_t)s1 * 64 + lane];
      unsigned int w2 = kvw[(size_t)s2 * 64 + lane];
      unsigned int w3 = kvw[(size_t)s3 * 64 + lane];
      float a0 = __uint_as_float(((unsigned int)*(const unsigned short*)&eab[(size_t)(j + 0) * 32 + el]) << 16);
      float a1 = __uint_as_float(((unsigned int)*(const unsigned short*)&eab[(size_t)(j + 1) * 32 + el]) << 16);
      float a2 = __uint_as_float(((unsigned int)*(const unsigned short*)&eab[(size_t)(j + 2) * 32 + el]) << 16);
      float a3 = __uint_as_float(((unsigned int)*(const unsigned short*)&eab[(size_t)(j + 3) * 32 + el]) << 16);
      float k0 = __uint_as_float(w0 << 16), v0 = __uint_as_float(w0 & 0xFFFF0000u);
      float k1 = __uint_as_float(w1 << 16), v1 = __uint_as_float(w1 & 0xFFFF0000u);
      float k2 = __uint_as_float(w2 << 16), v2 = __uint_as_float(w2 & 0xFFFF0000u);
      float k3 = __uint_as_float(w3 << 16), v3 = __uint_as_float(w3 & 0xFFFF0000u);
      float x0 = fmaf(q_c, k0, qe_c * a0);
      float x1 = fmaf(q_c, k1, qe_c * a1);
      float x2 = fmaf(q_c, k2, qe_c * a2);
      float x3 = fmaf(q_c, k3, qe_c * a3);
#pragma unroll
      for (int off = 1; off < RW; off <<= 1) {
        x0 += __shfl_xor(x0, off);
        x1 += __shfl_xor(x1, off);
        x2 += __shfl_xor(x2, off);
        x3 += __shfl_xor(x3, off);
      }
      float mx = fmaxf(fmaxf(x0, x1), fmaxf(x2, x3));
      if (__any(mx > m + 16.f)) {  // rare rescale (defer-max, T=16 in log2 units)
        float mn = fmaxf(m, mx);
        float sc = exp2f(m - mn);
        s *= sc; accv *= sc; acce *= sc;
        m = mn;
      }
      float q0 = exp2f(x0 - m), q1 = exp2f(x1 - m);
      float q2 = exp2f(x2 - m), q3 = exp2f(x3 - m);
      s += (q0 + q1) + (q2 + q3);
      accv += fmaf(q0, v0, q1 * v1) + fmaf(q2, v2, q3 * v3);
      acce += fmaf(q0, a0, q1 * a1) + fmaf(q2, a2, q3 * a3);
    }
    for (; j < je; ++j) {
      int s0 = srcs[j];
      unsigned int w0 = kvw[(size_t)s0 * 64 + lane];
      float k0 = __uint_as_float(w0 << 16), v0 = __uint_as_float(w0 & 0xFFFF0000u);
      float a0 = __uint_as_float(((unsigned int)*(const unsigned short*)&eab[(size_t)j * 32 + el]) << 16);
      float x0 = fmaf(q_c, k0, qe_c * a0);
#pragma unroll
      for (int off = 1; off < RW; off <<= 1) x0 += __shfl_xor(x0, off);
      float mn = fmaxf(m, x0);
      float sc = exp2f(m - mn);
      float q0 = exp2f(x0 - mn);
      s = s * sc + q0;
      accv = accv * sc + q0 * v0;
      acce = acce * sc + q0 * a0;
      m = mn;
    }

    // epilogue: out = (accv + aea @ We)/(s+eps) + skip [; prelu]
    int base = (H == 2) ? (lane & 32) : 0;
    float sum = accv;
#pragma unroll
    for (int d = 0; d < 32; ++d) {
      float aead = __shfl(acce, base + d);
      sum = fmaf(aead, wecol[d], sum);
    }
    float out = sum / (s + 1e-16f);
    out += qs[(size_t)dst * 128 + 64 + lane];
    if (!LAST) out = (out >= 0.f) ? out : pa * out;
    hout[(size_t)dst * 64 + lane] = out;
  }
}

extern "C" void kernel_launch(void* const* d_in, const int* in_sizes, int n_in,
                              void* d_out, int out_size, void* d_ws, size_t ws_size,
                              hipStream_t stream) {
  const int N = in_sizes[0] / NDIM;   // 50000
  const int E = in_sizes[2] / 2;      // 800000

  const float* x  = (const float*)d_in[0];
  const float* ea = (const float*)d_in[1];
  const int* ei   = (const int*)d_in[2];
  const float* prelu = (const float*)d_in[30];
  auto W = [&](int l, int k) { return (const float*)d_in[3 + 9 * l + k]; };
  // k: 0=Wq 1=bq 2=Wk 3=bk 4=Wv 5=bv 6=We 7=Ws 8=bs

  const int nbScan = (N + 1023) / 1024;  // 49

  char* p = (char*)d_ws;
  auto alloc = [&](size_t bytes) { char* r = p; p += (bytes + 255) & ~(size_t)255; return r; };
  float* h             = (float*)alloc((size_t)N * 64 * 4);
  float* qs            = (float*)alloc((size_t)N * 128 * 4);
  unsigned int* kvw    = (unsigned int*)alloc((size_t)N * 64 * 4);
  float* qe            = (float*)alloc((size_t)N * 64 * 4);
  __hip_bfloat16* eab  = (__hip_bfloat16*)alloc((size_t)E * 32 * 2);
  int* rowptr          = (int*)alloc((size_t)(N + 1) * 4);
  int* cntfill         = (int*)alloc((size_t)2 * N * 4);  // cnt | fill adjacent
  int* cnt = cntfill;
  int* fill = cntfill + N;
  int* srcs            = (int*)alloc((size_t)E * 4);
  int* perm            = (int*)alloc((size_t)E * 4);
  int* tpre            = (int*)alloc((size_t)nbScan * 256 * 4);
  int* btot            = (int*)alloc((size_t)64 * 4);
  (void)ws_size; (void)n_in; (void)out_size;

  hipMemsetAsync(cntfill, 0, (size_t)2 * N * 4, stream);

  k_count<<<(E + 255) / 256, 256, 0, stream>>>(ei, cnt, E);
  k_scanA<<<nbScan, 256, 0, stream>>>(cnt, tpre, btot, N);
  k_scanB<<<1, 64, 0, stream>>>(btot, nbScan, rowptr, N);
  k_scanC<<<nbScan, 256, 0, stream>>>(cnt, tpre, btot, rowptr, N);
  k_scatter<<<(E + 255) / 256, 256, 0, stream>>>(ei, fill, rowptr, srcs, perm, E);
  k_permea<<<(E * 8 + 255) / 256, 256, 0, stream>>>(perm, (const float4*)ea, (ushort4*)eab, E);

  const int attnBlocks = (N + 15) / 16;  // 4 waves x 4 dsts per block
  for (int l = 0; l < 3; ++l) {
    const float* hin = (l == 0) ? x : h;
    if (l < 2) {
      k_node<2><<<(N + 63) / 64, 256, 0, stream>>>(
          hin, W(l, 0), W(l, 1), W(l, 2), W(l, 3), W(l, 4), W(l, 5), W(l, 7), W(l, 8),
          W(l, 6), qs, kvw, qe, N);
      k_attn<2, false><<<attnBlocks, 256, 0, stream>>>(
          qs, kvw, qe, eab, W(l, 6), rowptr, srcs, prelu, h, N);
    } else {
      k_node<1><<<(N + 63) / 64, 256, 0, stream>>>(
          hin, W(l, 0), W(l, 1), W(l, 2), W(l, 3), W(l, 4), W(l, 5), W(l, 7), W(l, 8),
          W(l, 6), qs, kvw, qe, N);
      k_attn<1, true><<<attnBlocks, 256, 0, stream>>>(
          qs, kvw, qe, eab, W(l, 6), rowptr, srcs, prelu, (float*)d_out, N);
    }
  }
}

// Round 8
// 683.895 us; speedup vs baseline: 1.7751x; 1.1466x over previous
//
#include <hip/hip_runtime.h>
#include <hip/hip_bf16.h>

// GaussianGraphNetwork: 3-layer TransformerConv (PyG-style) on MI355X. f32 I/O.
// N=50000, E=800000, all layers din=64, H*C=64, skip=64, DE=32.
// r7 post-mortem: 4-dst rep loop regressed attn (101us, occ 40%); 480us outside attn.
// r8: revert attn to wave-per-dst (r6) + kvw dword; drop permea (original-order eab
// via int2 pairs); fuse ea->bf16 convert into k_count; scatter writes one int2.

#define NDIM 64

static __device__ __forceinline__ unsigned short f2bu(float f) {
  __hip_bfloat16 b = __float2bfloat16(f);
  return *reinterpret_cast<unsigned short*>(&b);
}

// ---------- count + edge_attr convert (fused; 8 threads per edge) ----------
__global__ __launch_bounds__(256) void k_count_cvt(
    const int* __restrict__ ei, int* __restrict__ cnt,
    const float4* __restrict__ ea, ushort4* __restrict__ eab, int E) {
  int tid = blockIdx.x * 256 + threadIdx.x;
  int pos = tid >> 3, t = tid & 7;
  if (pos >= E) return;
  float4 v = ea[(size_t)pos * 8 + t];
  ushort4 u;
  u.x = f2bu(v.x); u.y = f2bu(v.y); u.z = f2bu(v.z); u.w = f2bu(v.w);
  eab[(size_t)pos * 8 + t] = u;
  if (t == 0) atomicAdd(&cnt[ei[E + pos]], 1);
}

// ---------- 3-phase parallel scan ----------
__global__ __launch_bounds__(256) void k_scanA(const int* __restrict__ cnt,
                                               int* __restrict__ tpre,
                                               int* __restrict__ btot, int n) {
  int t = threadIdx.x, b = blockIdx.x;
  int base = (b * 256 + t) * 4;
  int s = 0;
  if (base + 3 < n) {
    int4 v = *(const int4*)(cnt + base);
    s = v.x + v.y + v.z + v.w;
  } else if (base < n) {
    for (int k = 0; k < 4 && base + k < n; ++k) s += cnt[base + k];
  }
  __shared__ int ps[256];
  ps[t] = s;
  __syncthreads();
  for (int off = 1; off < 256; off <<= 1) {
    int v = (t >= off) ? ps[t - off] : 0;
    __syncthreads();
    ps[t] += v;
    __syncthreads();
  }
  tpre[b * 256 + t] = ps[t] - s;
  if (t == 255) btot[b] = ps[255];
}

__global__ void k_scanB(int* __restrict__ btot, int nb, int* __restrict__ rowptr, int n) {
  int lane = threadIdx.x & 63;
  int v = (lane < nb) ? btot[lane] : 0;
  int inc = v;
#pragma unroll
  for (int off = 1; off < 64; off <<= 1) {
    int u = __shfl_up(inc, off);
    if (lane >= off) inc += u;
  }
  if (lane < nb) btot[lane] = inc - v;
  if (lane == 63) rowptr[n] = inc;
}

__global__ __launch_bounds__(256) void k_scanC(const int* __restrict__ cnt,
                                               const int* __restrict__ tpre,
                                               const int* __restrict__ btot,
                                               int* __restrict__ rowptr, int n) {
  int t = threadIdx.x, b = blockIdx.x;
  int base = (b * 256 + t) * 4;
  if (base >= n) return;
  int p = btot[b] + tpre[b * 256 + t];
  if (base + 3 < n) {
    int4 v = *(const int4*)(cnt + base);
    rowptr[base] = p; p += v.x;
    rowptr[base + 1] = p; p += v.y;
    rowptr[base + 2] = p; p += v.z;
    rowptr[base + 3] = p;
  } else {
    for (int k = 0; k < 4 && base + k < n; ++k) { rowptr[base + k] = p; p += cnt[base + k]; }
  }
}

// ---------- scatter: pairs[pos] = (src, eid), one 8B write per edge ----------
__global__ void k_scatter(const int* __restrict__ ei, int* __restrict__ fill,
                          const int* __restrict__ rowptr, int2* __restrict__ pairs, int E) {
  int i = blockIdx.x * blockDim.x + threadIdx.x;
  if (i < E) {
    int d = ei[E + i];
    int pos = rowptr[d] + atomicAdd(&fill[d], 1);
    pairs[pos] = make_int2(ei[i], i);
  }
}

// ---------- node GEMM + fused qe ----------
// outputs: qs f32 [N][128] = q|skip ; kvw uint [N][64] = (v<<16|k) ; qe f32 [N][64]
template <int H>
__global__ __launch_bounds__(256) void k_node(
    const float* __restrict__ h,
    const float* __restrict__ Wq, const float* __restrict__ bq,
    const float* __restrict__ Wk, const float* __restrict__ bk,
    const float* __restrict__ Wv, const float* __restrict__ bv,
    const float* __restrict__ Ws, const float* __restrict__ bs,
    const float* __restrict__ We,
    float* __restrict__ qs, unsigned int* __restrict__ kvw,
    float* __restrict__ qe, int N)
{
  __shared__ float hL[64][64];
  __shared__ float qL[64][64];
  __shared__ float WeT[2048];  // WeT[hc*32+d] = We[d*64+hc]
  int t = threadIdx.x;
  int nb = blockIdx.x * 64;
  int m = t >> 6, c = t & 63;
  const float* W = (m == 0) ? Wq : (m == 1) ? Wk : (m == 2) ? Wv : Ws;
  const float* B = (m == 0) ? bq : (m == 1) ? bk : (m == 2) ? bv : bs;
  float w[64];
#pragma unroll
  for (int d = 0; d < 64; ++d) w[d] = W[d * 64 + c];
  float bias = B[c];
#pragma unroll
  for (int f = t; f < 2048; f += 256) WeT[(f >> 5) * 32 + (f & 31)] = We[(f & 31) * 64 + (f >> 5)];
  int nmax = N - nb; if (nmax > 64) nmax = 64;
#pragma unroll
  for (int j = 0; j < 16; ++j) {
    int flat = j * 256 + t;
    int ni = flat >> 6;
    if (ni < nmax) hL[ni][flat & 63] = h[(size_t)(nb + ni) * 64 + (flat & 63)];
  }
  __syncthreads();
  for (int i = 0; i < nmax; ++i) {
    float acc = bias;
    const float4* hr = (const float4*)&hL[i][0];
#pragma unroll
    for (int d4 = 0; d4 < 16; ++d4) {
      float4 hv = hr[d4];
      acc = fmaf(hv.x, w[4 * d4 + 0], acc);
      acc = fmaf(hv.y, w[4 * d4 + 1], acc);
      acc = fmaf(hv.z, w[4 * d4 + 2], acc);
      acc = fmaf(hv.w, w[4 * d4 + 3], acc);
    }
    size_t n = (size_t)(nb + i);
    if (m == 0)      { qs[n * 128 + c] = acc; qL[i][c] = acc; }
    else if (m == 3) qs[n * 128 + 64 + c] = acc;
    else ((unsigned short*)kvw)[(n * 64 + c) * 2 + (m == 2 ? 1 : 0)] = f2bu(acc);
  }
  __syncthreads();
  // qe phase
  int slot = t & 63, ibase = (t >> 6) * 16;
  int half = slot >> 5, d = slot & 31;
  float wreg[32];
#pragma unroll
  for (int cc = 0; cc < 32; ++cc) wreg[cc] = WeT[(half * 32 + cc) * 32 + d];
  for (int ii = 0; ii < 16; ++ii) {
    int i = ibase + ii;
    if (i >= nmax) break;
    float acc = 0.f;
    const float4* qr = (const float4*)&qL[i][half * 32];
#pragma unroll
    for (int c4 = 0; c4 < 8; ++c4) {
      float4 qv = qr[c4];
      acc = fmaf(qv.x, wreg[4 * c4 + 0], acc);
      acc = fmaf(qv.y, wreg[4 * c4 + 1], acc);
      acc = fmaf(qv.z, wreg[4 * c4 + 2], acc);
      acc = fmaf(qv.w, wreg[4 * c4 + 3], acc);
    }
    size_t n = (size_t)(nb + i);
    if (H == 2) {
      qe[n * 64 + slot] = acc;
    } else {
      float tot = acc + __shfl_xor(acc, 32);
      qe[n * 64 + slot] = (slot < 32) ? tot : 0.f;
    }
  }
}

// ---------- fused attention: one wave = one dst, lane = channel ----------
template <int H, bool LAST>
__global__ __launch_bounds__(256) void k_attn(
    const float* __restrict__ qs,            // [N][128]: q|skip
    const unsigned int* __restrict__ kvw,    // [N][64]: v<<16|k
    const float* __restrict__ qe,            // [N][64]
    const __hip_bfloat16* __restrict__ eab,  // [E][32] original edge order
    const float* __restrict__ We,            // [32][64]
    const int* __restrict__ rowptr,
    const int2* __restrict__ pairs,          // (src, eid) CSR-ordered
    const float* __restrict__ prelu_a,
    float* __restrict__ hout, int N)
{
  int wave = threadIdx.x >> 6;
  int lane = threadIdx.x & 63;
  int dst = blockIdx.x * 4 + wave;
  if (dst >= N) return;
  const float rsC = (H == 2) ? 0.17677669529663687f : 0.125f;
  const int RW = (H == 2) ? 32 : 64;
  int el = lane & 31;

  float q_c = qs[(size_t)dst * 128 + lane];
  float qe_c = qe[(size_t)dst * 64 + lane];

  float m = -1e30f, s = 0.f, accv = 0.f, acce = 0.f;
  int jb = rowptr[dst], je = rowptr[dst + 1];
  int j = jb;
  for (; j + 4 <= je; j += 4) {
    int2 p0 = pairs[j], p1 = pairs[j + 1], p2 = pairs[j + 2], p3 = pairs[j + 3];
    unsigned int w0 = kvw[(size_t)p0.x * 64 + lane];
    unsigned int w1 = kvw[(size_t)p1.x * 64 + lane];
    unsigned int w2 = kvw[(size_t)p2.x * 64 + lane];
    unsigned int w3 = kvw[(size_t)p3.x * 64 + lane];
    float a0 = __uint_as_float(((unsigned int)*(const unsigned short*)&eab[(size_t)p0.y * 32 + el]) << 16);
    float a1 = __uint_as_float(((unsigned int)*(const unsigned short*)&eab[(size_t)p1.y * 32 + el]) << 16);
    float a2 = __uint_as_float(((unsigned int)*(const unsigned short*)&eab[(size_t)p2.y * 32 + el]) << 16);
    float a3 = __uint_as_float(((unsigned int)*(const unsigned short*)&eab[(size_t)p3.y * 32 + el]) << 16);
    float k0 = __uint_as_float(w0 << 16), v0 = __uint_as_float(w0 & 0xFFFF0000u);
    float k1 = __uint_as_float(w1 << 16), v1 = __uint_as_float(w1 & 0xFFFF0000u);
    float k2 = __uint_as_float(w2 << 16), v2 = __uint_as_float(w2 & 0xFFFF0000u);
    float k3 = __uint_as_float(w3 << 16), v3 = __uint_as_float(w3 & 0xFFFF0000u);
    float x0 = fmaf(q_c, k0, qe_c * a0);
    float x1 = fmaf(q_c, k1, qe_c * a1);
    float x2 = fmaf(q_c, k2, qe_c * a2);
    float x3 = fmaf(q_c, k3, qe_c * a3);
#pragma unroll
    for (int off = 1; off < RW; off <<= 1) {
      x0 += __shfl_xor(x0, off);
      x1 += __shfl_xor(x1, off);
      x2 += __shfl_xor(x2, off);
      x3 += __shfl_xor(x3, off);
    }
    x0 *= rsC; x1 *= rsC; x2 *= rsC; x3 *= rsC;
    float mx = fmaxf(fmaxf(x0, x1), fmaxf(x2, x3));
    float mn = fmaxf(m, mx);
    float sc = __expf(m - mn);
    float q0 = __expf(x0 - mn), q1 = __expf(x1 - mn);
    float q2 = __expf(x2 - mn), q3 = __expf(x3 - mn);
    s = s * sc + ((q0 + q1) + (q2 + q3));
    accv = accv * sc + (fmaf(q0, v0, q1 * v1) + fmaf(q2, v2, q3 * v3));
    acce = acce * sc + (fmaf(q0, a0, q1 * a1) + fmaf(q2, a2, q3 * a3));
    m = mn;
  }
  for (; j < je; ++j) {
    int2 p0 = pairs[j];
    unsigned int w0 = kvw[(size_t)p0.x * 64 + lane];
    float k0 = __uint_as_float(w0 << 16), v0 = __uint_as_float(w0 & 0xFFFF0000u);
    float a0 = __uint_as_float(((unsigned int)*(const unsigned short*)&eab[(size_t)p0.y * 32 + el]) << 16);
    float x0 = fmaf(q_c, k0, qe_c * a0);
#pragma unroll
    for (int off = 1; off < RW; off <<= 1) x0 += __shfl_xor(x0, off);
    x0 *= rsC;
    float mn = fmaxf(m, x0);
    float sc = __expf(m - mn);
    float q0 = __expf(x0 - mn);
    s = s * sc + q0;
    accv = accv * sc + q0 * v0;
    acce = acce * sc + q0 * a0;
    m = mn;
  }

  // epilogue
  float wecol[32];
#pragma unroll
  for (int d = 0; d < 32; ++d) wecol[d] = We[d * 64 + lane];
  int base = (H == 2) ? (lane & 32) : 0;
  float sum = accv;
#pragma unroll
  for (int d = 0; d < 32; ++d) {
    float aead = __shfl(acce, base + d);
    sum = fmaf(aead, wecol[d], sum);
  }
  float out = sum / (s + 1e-16f);
  out += qs[(size_t)dst * 128 + 64 + lane];
  if (!LAST) {
    float a = prelu_a[0];
    out = (out >= 0.f) ? out : a * out;
  }
  hout[(size_t)dst * 64 + lane] = out;
}

extern "C" void kernel_launch(void* const* d_in, const int* in_sizes, int n_in,
                              void* d_out, int out_size, void* d_ws, size_t ws_size,
                              hipStream_t stream) {
  const int N = in_sizes[0] / NDIM;   // 50000
  const int E = in_sizes[2] / 2;      // 800000

  const float* x  = (const float*)d_in[0];
  const float* ea = (const float*)d_in[1];
  const int* ei   = (const int*)d_in[2];
  const float* prelu = (const float*)d_in[30];
  auto W = [&](int l, int k) { return (const float*)d_in[3 + 9 * l + k]; };

  const int nbScan = (N + 1023) / 1024;  // 49

  char* p = (char*)d_ws;
  auto alloc = [&](size_t bytes) { char* r = p; p += (bytes + 255) & ~(size_t)255; return r; };
  float* h             = (float*)alloc((size_t)N * 64 * 4);
  float* qs            = (float*)alloc((size_t)N * 128 * 4);
  unsigned int* kvw    = (unsigned int*)alloc((size_t)N * 64 * 4);
  float* qe            = (float*)alloc((size_t)N * 64 * 4);
  __hip_bfloat16* eab  = (__hip_bfloat16*)alloc((size_t)E * 32 * 2);
  int* rowptr          = (int*)alloc((size_t)(N + 1) * 4);
  int* cntfill         = (int*)alloc((size_t)2 * N * 4);
  int* cnt = cntfill;
  int* fill = cntfill + N;
  int2* pairs          = (int2*)alloc((size_t)E * 8);
  int* tpre            = (int*)alloc((size_t)nbScan * 256 * 4);
  int* btot            = (int*)alloc((size_t)64 * 4);
  (void)ws_size; (void)n_in; (void)out_size;

  hipMemsetAsync(cntfill, 0, (size_t)2 * N * 4, stream);

  k_count_cvt<<<(E * 8 + 255) / 256, 256, 0, stream>>>(ei, cnt, (const float4*)ea,
                                                       (ushort4*)eab, E);
  k_scanA<<<nbScan, 256, 0, stream>>>(cnt, tpre, btot, N);
  k_scanB<<<1, 64, 0, stream>>>(btot, nbScan, rowptr, N);
  k_scanC<<<nbScan, 256, 0, stream>>>(cnt, tpre, btot, rowptr, N);
  k_scatter<<<(E + 255) / 256, 256, 0, stream>>>(ei, fill, rowptr, pairs, E);

  for (int l = 0; l < 3; ++l) {
    const float* hin = (l == 0) ? x : h;
    if (l < 2) {
      k_node<2><<<(N + 63) / 64, 256, 0, stream>>>(
          hin, W(l, 0), W(l, 1), W(l, 2), W(l, 3), W(l, 4), W(l, 5), W(l, 7), W(l, 8),
          W(l, 6), qs, kvw, qe, N);
      k_attn<2, false><<<(N + 3) / 4, 256, 0, stream>>>(
          qs, kvw, qe, eab, W(l, 6), rowptr, pairs, prelu, h, N);
    } else {
      k_node<1><<<(N + 63) / 64, 256, 0, stream>>>(
          hin, W(l, 0), W(l, 1), W(l, 2), W(l, 3), W(l, 4), W(l, 5), W(l, 7), W(l, 8),
          W(l, 6), qs, kvw, qe, N);
      k_attn<1, true><<<(N + 3) / 4, 256, 0, stream>>>(
          qs, kvw, qe, eab, W(l, 6), rowptr, pairs, prelu, (float*)d_out, N);
    }
  }
}